// Round 1
// baseline (390.704 us; speedup 1.0000x reference)
//
#include <hip/hip_runtime.h>
#include <stdint.h>

#define DM 1024
#define SEQ 2048
#define MTOT 8192   // 4*2048

typedef __attribute__((ext_vector_type(8))) short bf16x8;
typedef __attribute__((ext_vector_type(4))) float f32x4;
typedef __attribute__((ext_vector_type(8))) unsigned short u16x8;

__device__ __forceinline__ unsigned short f2bf(float x) {
  uint32_t u = __builtin_bit_cast(uint32_t, x);
  u += 0x7fffu + ((u >> 16) & 1u);   // RTNE
  return (unsigned short)(u >> 16);
}

__device__ __forceinline__ void gload16(void* lds, const void* g) {
  __builtin_amdgcn_global_load_lds(
      (const __attribute__((address_space(1))) void*)(uintptr_t)g,
      (__attribute__((address_space(3))) void*)(uintptr_t)lds,
      16, 0, 0);
}

// ---------------- weight transpose + bf16 convert: Wt[n][k] = bf16(W[k][n])
__global__ __launch_bounds__(256)
void prep_w(const float* __restrict__ w0, const float* __restrict__ w1,
            const float* __restrict__ w2, const float* __restrict__ w3,
            unsigned short* __restrict__ Wt) {
  const int z = blockIdx.z;
  const float* W = z == 0 ? w0 : z == 1 ? w1 : z == 2 ? w2 : w3;
  unsigned short* out = Wt + (size_t)z * 1048576;
  __shared__ float tile[32][33];
  const int n0 = blockIdx.x * 32, k0 = blockIdx.y * 32;
  const int tx = threadIdx.x & 31, ty = threadIdx.x >> 5;
#pragma unroll
  for (int j = 0; j < 32; j += 8)
    tile[ty + j][tx] = W[(size_t)(k0 + ty + j) * DM + n0 + tx];
  __syncthreads();
#pragma unroll
  for (int j = 0; j < 32; j += 8)
    out[(size_t)(n0 + ty + j) * DM + k0 + tx] = f2bf(tile[tx][ty + j]);
}

// ---------------- fp32 -> bf16 bulk convert (8 elems/thread)
__global__ __launch_bounds__(256)
void cvt_f32_bf16(const float* __restrict__ in, unsigned short* __restrict__ out, int n8) {
  int i = blockIdx.x * 256 + threadIdx.x;
  if (i < n8) {
    f32x4 a = *(const f32x4*)(in + (size_t)i * 8);
    f32x4 b = *(const f32x4*)(in + (size_t)i * 8 + 4);
    u16x8 o;
#pragma unroll
    for (int j = 0; j < 4; ++j) { o[j] = f2bf(a[j]); o[4 + j] = f2bf(b[j]); }
    *(u16x8*)(out + (size_t)i * 8) = o;
  }
}

// ---------------- bf16 GEMM: C[M][1024] = A[M][1024] @ Wt^T + bias
// Wt is [n][k] row-major bf16. 128x128 tile, BK=64, 4 waves, 16x16x32 MFMA.
template <bool OUT_F32>
__global__ __launch_bounds__(256)
void gemm_bt(const unsigned short* __restrict__ A,
             const unsigned short* __restrict__ Wt,
             const float* __restrict__ bias,
             void* __restrict__ C) {
  __shared__ char sA[16384];   // [128 rows][64 bf16 = 128B], XOR-swizzled
  __shared__ char sB[16384];
  const int t = threadIdx.x, wave = t >> 6, lane = t & 63;
  const int m0 = blockIdx.y * 128, n0 = blockIdx.x * 128;
  const int wr = (wave >> 1) * 64, wc = (wave & 1) * 64;
  const int lr = lane & 15, kg = lane >> 4;

  f32x4 acc[4][4];
#pragma unroll
  for (int i = 0; i < 4; ++i)
#pragma unroll
    for (int j = 0; j < 4; ++j) acc[i][j] = (f32x4){0.f, 0.f, 0.f, 0.f};

  for (int kt = 0; kt < 16; ++kt) {
    __syncthreads();
    // stage: 16 chunks x 1KB (8 rows x 128B), linear LDS, pre-swizzled source
#pragma unroll
    for (int i = 0; i < 4; ++i) {
      int c = wave * 4 + i;
      int row = c * 8 + (lane >> 3);
      int bo = ((lane & 7) * 16) ^ ((row & 7) << 4);
      gload16(&sA[c * 1024], (const char*)(A + (size_t)(m0 + row) * DM + kt * 64) + bo);
      gload16(&sB[c * 1024], (const char*)(Wt + (size_t)(n0 + row) * DM + kt * 64) + bo);
    }
    __syncthreads();
#pragma unroll
    for (int ks = 0; ks < 2; ++ks) {
      bf16x8 afr[4], bfr[4];
#pragma unroll
      for (int j = 0; j < 4; ++j) {
        int mr = wr + j * 16 + lr;
        afr[j] = *(const bf16x8*)&sA[mr * 128 + ((ks * 64 + kg * 16) ^ ((mr & 7) << 4))];
        int nr = wc + j * 16 + lr;
        bfr[j] = *(const bf16x8*)&sB[nr * 128 + ((ks * 64 + kg * 16) ^ ((nr & 7) << 4))];
      }
#pragma unroll
      for (int mi = 0; mi < 4; ++mi)
#pragma unroll
        for (int nj = 0; nj < 4; ++nj)
          acc[mi][nj] = __builtin_amdgcn_mfma_f32_16x16x32_bf16(afr[mi], bfr[nj], acc[mi][nj], 0, 0, 0);
    }
  }
  // epilogue: C/D layout col=lane&15, row=(lane>>4)*4+r
#pragma unroll
  for (int nj = 0; nj < 4; ++nj) {
    int col = n0 + wc + nj * 16 + lr;
    float bv = bias[col];
#pragma unroll
    for (int mi = 0; mi < 4; ++mi) {
      int row = m0 + wr + mi * 16 + kg * 4;
#pragma unroll
      for (int r = 0; r < 4; ++r) {
        float v = acc[mi][nj][r] + bv;
        if (OUT_F32) ((float*)C)[(size_t)(row + r) * DM + col] = v;
        else ((unsigned short*)C)[(size_t)(row + r) * DM + col] = f2bf(v);
      }
    }
  }
}

// ---------------- flash attention: one block = (b,h) x 64 q-rows; 4 waves x 16 rows
__global__ __launch_bounds__(256)
void attn(const unsigned short* __restrict__ Qb,
          const unsigned short* __restrict__ Kb,
          const unsigned short* __restrict__ Vb,
          unsigned short* __restrict__ Ctx) {
  __shared__ char sK[8192];    // [64 keys][64 bf16], swizzled
  __shared__ char sVt[8192];   // [64 d][64 keys], swizzled (transposed V)
  __shared__ char sP[8192];    // per-wave [16 q][64 keys], swizzled
  const int t = threadIdx.x, wave = t >> 6, lane = t & 63;
  const int lr = lane & 15, kg = lane >> 4;
  const int bh = blockIdx.x;
  const int b = bh >> 4, h = bh & 15;
  const int q0 = blockIdx.y * 64;
  const size_t seqbase = (size_t)b * SEQ * DM + h * 64;

  // Q fragments in registers (A-operand: row=lane&15, k = (lane>>4)*8.. contiguous)
  bf16x8 qf[2];
#pragma unroll
  for (int ks = 0; ks < 2; ++ks)
    qf[ks] = *(const bf16x8*)(Qb + seqbase + (size_t)(q0 + wave * 16 + lr) * DM + ks * 32 + kg * 8);

  f32x4 o[4];
#pragma unroll
  for (int dt = 0; dt < 4; ++dt) o[dt] = (f32x4){0.f, 0.f, 0.f, 0.f};
  float m[4] = {-1e30f, -1e30f, -1e30f, -1e30f};
  float l[4] = {0.f, 0.f, 0.f, 0.f};

  for (int kt = 0; kt < SEQ / 64; ++kt) {
    __syncthreads();
    // stage K tile (8KB) via global_load_lds
#pragma unroll
    for (int i = 0; i < 2; ++i) {
      int c = wave * 2 + i;
      int row = c * 8 + (lane >> 3);
      int bo = ((lane & 7) * 16) ^ ((row & 7) << 4);
      gload16(&sK[c * 1024], (const char*)(Kb + seqbase + (size_t)(kt * 64 + row) * DM) + bo);
    }
    // stage V transposed (reg path): thread -> 16 elems of one key row
    {
      int key = t >> 2, dp = t & 3;
      const unsigned short* src = Vb + seqbase + (size_t)(kt * 64 + key) * DM + dp * 16;
      u16x8 v0 = *(const u16x8*)src;
      u16x8 v1 = *(const u16x8*)(src + 8);
#pragma unroll
      for (int j = 0; j < 8; ++j) {
        int d = dp * 16 + j;
        *(unsigned short*)&sVt[d * 128 + ((key * 2) ^ ((d & 7) << 4))] = (unsigned short)v0[j];
      }
#pragma unroll
      for (int j = 0; j < 8; ++j) {
        int d = dp * 16 + 8 + j;
        *(unsigned short*)&sVt[d * 128 + ((key * 2) ^ ((d & 7) << 4))] = (unsigned short)v1[j];
      }
    }
    __syncthreads();

    // S = Q K^T  (raw, scale later)
    f32x4 s[4];
#pragma unroll
    for (int nt = 0; nt < 4; ++nt) s[nt] = (f32x4){0.f, 0.f, 0.f, 0.f};
#pragma unroll
    for (int ks = 0; ks < 2; ++ks)
#pragma unroll
      for (int nt = 0; nt < 4; ++nt) {
        int krow = nt * 16 + lr;
        bf16x8 kf = *(const bf16x8*)&sK[krow * 128 + ((ks * 64 + kg * 16) ^ ((krow & 7) << 4))];
        s[nt] = __builtin_amdgcn_mfma_f32_16x16x32_bf16(qf[ks], kf, s[nt], 0, 0, 0);
      }

    // online softmax; row q = kg*4+r lives across the 16 lanes sharing kg
    float alpha[4], rs[4];
#pragma unroll
    for (int r = 0; r < 4; ++r) {
      float v = fmaxf(fmaxf(s[0][r], s[1][r]), fmaxf(s[2][r], s[3][r]));
      v = fmaxf(v, __shfl_xor(v, 1));
      v = fmaxf(v, __shfl_xor(v, 2));
      v = fmaxf(v, __shfl_xor(v, 4));
      v = fmaxf(v, __shfl_xor(v, 8));
      float mn = fmaxf(m[r], v * 0.125f);
      alpha[r] = __expf(m[r] - mn);
      m[r] = mn;
      rs[r] = 0.f;
    }
#pragma unroll
    for (int nt = 0; nt < 4; ++nt) {
      int key2 = (nt * 16 + lr) * 2;
#pragma unroll
      for (int r = 0; r < 4; ++r) {
        float p = __expf(s[nt][r] * 0.125f - m[r]);
        rs[r] += p;
        int q = kg * 4 + r;
        *(unsigned short*)&sP[wave * 2048 + q * 128 + (key2 ^ ((q & 7) << 4))] = f2bf(p);
      }
    }
#pragma unroll
    for (int r = 0; r < 4; ++r) {
      float v = rs[r];
      v += __shfl_xor(v, 1);
      v += __shfl_xor(v, 2);
      v += __shfl_xor(v, 4);
      v += __shfl_xor(v, 8);
      l[r] = l[r] * alpha[r] + v;
    }
    {
      f32x4 av = (f32x4){alpha[0], alpha[1], alpha[2], alpha[3]};
#pragma unroll
      for (int dt = 0; dt < 4; ++dt) o[dt] *= av;
    }
    // O += P @ V
#pragma unroll
    for (int ks = 0; ks < 2; ++ks) {
      bf16x8 pf = *(const bf16x8*)&sP[wave * 2048 + lr * 128 + ((ks * 64 + kg * 16) ^ ((lr & 7) << 4))];
#pragma unroll
      for (int dt = 0; dt < 4; ++dt) {
        int d = dt * 16 + lr;
        bf16x8 vf = *(const bf16x8*)&sVt[d * 128 + ((ks * 64 + kg * 16) ^ ((d & 7) << 4))];
        o[dt] = __builtin_amdgcn_mfma_f32_16x16x32_bf16(pf, vf, o[dt], 0, 0, 0);
      }
    }
  }

#pragma unroll
  for (int r = 0; r < 4; ++r) l[r] = 1.0f / l[r];
#pragma unroll
  for (int dt = 0; dt < 4; ++dt)
#pragma unroll
    for (int r = 0; r < 4; ++r) {
      int row = q0 + wave * 16 + kg * 4 + r;
      int col = dt * 16 + lr;
      Ctx[seqbase + (size_t)row * DM + col] = f2bf(o[dt][r] * l[r]);
    }
}

extern "C" void kernel_launch(void* const* d_in, const int* in_sizes, int n_in,
                              void* d_out, int out_size, void* d_ws, size_t ws_size,
                              hipStream_t stream) {
  const float* query = (const float*)d_in[0];
  const float* key   = (const float*)d_in[1];
  const float* value = (const float*)d_in[2];
  const float* Wq = (const float*)d_in[3];
  const float* bq = (const float*)d_in[4];
  const float* Wk = (const float*)d_in[5];
  const float* bk = (const float*)d_in[6];
  const float* Wv = (const float*)d_in[7];
  const float* bv = (const float*)d_in[8];
  const float* Wo = (const float*)d_in[9];
  const float* bo = (const float*)d_in[10];

  char* ws = (char*)d_ws;
  unsigned short* Wt = (unsigned short*)ws;                                   // 8 MB: [Wq^T,Wk^T,Wv^T,Wo^T] bf16
  unsigned short* Qb = (unsigned short*)(ws + 8388608);                       // 16 MB each
  unsigned short* Kb = (unsigned short*)(ws + 8388608 + 16777216);
  unsigned short* Vb = (unsigned short*)(ws + 8388608 + 2 * 16777216);
  unsigned short* Xc = (unsigned short*)(ws + 8388608 + 3 * 16777216);        // X buffer, reused as context

  prep_w<<<dim3(32, 32, 4), 256, 0, stream>>>(Wq, Wk, Wv, Wo, Wt);

  const float* ins[3] = {query, key, value};
  const float* bs[3]  = {bq, bk, bv};
  unsigned short* outs[3] = {Qb, Kb, Vb};
  for (int z = 0; z < 3; ++z) {
    cvt_f32_bf16<<<4096, 256, 0, stream>>>(ins[z], Xc, MTOT * DM / 8);
    gemm_bt<false><<<dim3(8, 64), 256, 0, stream>>>(Xc, Wt + (size_t)z * 1048576, bs[z], outs[z]);
  }

  attn<<<dim3(64, 32), 256, 0, stream>>>(Qb, Kb, Vb, Xc);

  gemm_bt<true><<<dim3(8, 64), 256, 0, stream>>>(Xc, Wt + (size_t)3 * 1048576, bo, d_out);
}

// Round 2
// 225.853 us; speedup vs baseline: 1.7299x; 1.7299x over previous
//
#include <hip/hip_runtime.h>
#include <stdint.h>

#define DM 1024
#define SEQ 2048
#define MTOT 8192   // 4*2048

typedef __attribute__((ext_vector_type(8))) short bf16x8;
typedef __attribute__((ext_vector_type(4))) float f32x4;
typedef __attribute__((ext_vector_type(16))) float f32x16;
typedef __attribute__((ext_vector_type(8))) unsigned short u16x8;
typedef __attribute__((ext_vector_type(4))) unsigned short u16x4;
typedef __attribute__((ext_vector_type(4))) uint32_t u32x4;

__device__ __forceinline__ unsigned short f2bf(float x) {
  uint32_t u = __builtin_bit_cast(uint32_t, x);
  u += 0x7fffu + ((u >> 16) & 1u);   // RTNE
  return (unsigned short)(u >> 16);
}

__device__ __forceinline__ uint32_t cvtpk_bf16(float lo, float hi) {
  uint32_t r;
  asm("v_cvt_pk_bf16_f32 %0, %1, %2" : "=v"(r) : "v"(lo), "v"(hi));
  return r;
}

__device__ __forceinline__ void gload16(void* lds, const void* g) {
  __builtin_amdgcn_global_load_lds(
      (const __attribute__((address_space(1))) void*)(uintptr_t)g,
      (__attribute__((address_space(3))) void*)(uintptr_t)lds,
      16, 0, 0);
}

// ---------------- weight transpose + bf16 convert: Wt[n][k] = bf16(W[k][n])
__global__ __launch_bounds__(256)
void prep_w(const float* __restrict__ w0, const float* __restrict__ w1,
            const float* __restrict__ w2, const float* __restrict__ w3,
            unsigned short* __restrict__ Wt) {
  const int z = blockIdx.z;
  const float* W = z == 0 ? w0 : z == 1 ? w1 : z == 2 ? w2 : w3;
  unsigned short* out = Wt + (size_t)z * 1048576;
  __shared__ float tile[32][33];
  const int n0 = blockIdx.x * 32, k0 = blockIdx.y * 32;
  const int tx = threadIdx.x & 31, ty = threadIdx.x >> 5;
#pragma unroll
  for (int j = 0; j < 32; j += 8)
    tile[ty + j][tx] = W[(size_t)(k0 + ty + j) * DM + n0 + tx];
  __syncthreads();
#pragma unroll
  for (int j = 0; j < 32; j += 8)
    out[(size_t)(n0 + ty + j) * DM + k0 + tx] = f2bf(tile[tx][ty + j]);
}

// ---------------- fp32 -> bf16 bulk convert (8 elems/thread)
__global__ __launch_bounds__(256)
void cvt_f32_bf16(const float* __restrict__ in, unsigned short* __restrict__ out, int n8) {
  int i = blockIdx.x * 256 + threadIdx.x;
  if (i < n8) {
    f32x4 a = *(const f32x4*)(in + (size_t)i * 8);
    f32x4 b = *(const f32x4*)(in + (size_t)i * 8 + 4);
    u16x8 o;
#pragma unroll
    for (int j = 0; j < 4; ++j) { o[j] = f2bf(a[j]); o[4 + j] = f2bf(b[j]); }
    *(u16x8*)(out + (size_t)i * 8) = o;
  }
}

// ---------------- bf16 GEMM: C[M][1024] = A[M][1024] @ Wt^T + bias
// Wt is [n][k] row-major bf16. 128x128 tile, BK=64, 4 waves, 16x16x32 MFMA.
// MODE 0: bf16 row-major out (scaled); MODE 1: f32 row-major out;
// MODE 2: bf16 V-transposed out: Vt[(b*16+h)*64+d][s] (d = col%1024 mapping)
template <int MODE>
__global__ __launch_bounds__(256)
void gemm_bt(const unsigned short* __restrict__ A,
             const unsigned short* __restrict__ Wt,
             const float* __restrict__ bias,
             void* __restrict__ C, float oscale) {
  __shared__ char sA[16384];   // [128 rows][64 bf16 = 128B], XOR-swizzled
  __shared__ char sB[16384];
  const int t = threadIdx.x, wave = t >> 6, lane = t & 63;
  const int m0 = blockIdx.y * 128, n0 = blockIdx.x * 128;
  const int wr = (wave >> 1) * 64, wc = (wave & 1) * 64;
  const int lr = lane & 15, kg = lane >> 4;

  f32x4 acc[4][4];
#pragma unroll
  for (int i = 0; i < 4; ++i)
#pragma unroll
    for (int j = 0; j < 4; ++j) acc[i][j] = (f32x4){0.f, 0.f, 0.f, 0.f};

  for (int kt = 0; kt < 16; ++kt) {
    __syncthreads();
#pragma unroll
    for (int i = 0; i < 4; ++i) {
      int c = wave * 4 + i;
      int row = c * 8 + (lane >> 3);
      int bo = ((lane & 7) * 16) ^ ((row & 7) << 4);
      gload16(&sA[c * 1024], (const char*)(A + (size_t)(m0 + row) * DM + kt * 64) + bo);
      gload16(&sB[c * 1024], (const char*)(Wt + (size_t)(n0 + row) * DM + kt * 64) + bo);
    }
    __syncthreads();
#pragma unroll
    for (int ks = 0; ks < 2; ++ks) {
      bf16x8 afr[4], bfr[4];
#pragma unroll
      for (int j = 0; j < 4; ++j) {
        int mr = wr + j * 16 + lr;
        afr[j] = *(const bf16x8*)&sA[mr * 128 + ((ks * 64 + kg * 16) ^ ((mr & 7) << 4))];
        int nr = wc + j * 16 + lr;
        bfr[j] = *(const bf16x8*)&sB[nr * 128 + ((ks * 64 + kg * 16) ^ ((nr & 7) << 4))];
      }
#pragma unroll
      for (int mi = 0; mi < 4; ++mi)
#pragma unroll
        for (int nj = 0; nj < 4; ++nj)
          acc[mi][nj] = __builtin_amdgcn_mfma_f32_16x16x32_bf16(afr[mi], bfr[nj], acc[mi][nj], 0, 0, 0);
    }
  }
  // epilogue: C/D layout col=lane&15, row=(lane>>4)*4+r
#pragma unroll
  for (int nj = 0; nj < 4; ++nj) {
    int col = n0 + wc + nj * 16 + lr;
    float bv = bias[col];
#pragma unroll
    for (int mi = 0; mi < 4; ++mi) {
      int rowseq = m0 + wr + mi * 16 + kg * 4;
      if (MODE == 2) {
        u16x4 pk;
#pragma unroll
        for (int r = 0; r < 4; ++r) pk[r] = f2bf(acc[mi][nj][r] + bv);
        // Vt[(b<<10) + col][s], s = rowseq & 2047, 4 consecutive s
        *(u16x4*)((unsigned short*)C +
                  ((size_t)((rowseq >> 11) << 10) + col) * SEQ + (rowseq & 2047)) = pk;
      } else {
#pragma unroll
        for (int r = 0; r < 4; ++r) {
          float v = (acc[mi][nj][r] + bv) * oscale;
          if (MODE == 1) ((float*)C)[(size_t)(rowseq + r) * DM + col] = v;
          else ((unsigned short*)C)[(size_t)(rowseq + r) * DM + col] = f2bf(v);
        }
      }
    }
  }
}

// ---------------- flash attention, swapped-operand 32x32x16 structure
// Block: 8 waves x 32 q-rows = 256 q for one (b,h). Lane owns q = lane&31.
// S^T = mfma(K, Q); softmax lane-local (exp2 domain, scale folded into Q);
// P^T B-frags built in-register (cvt_pk + cross-half exchange);
// O^T = mfma(Vt, P^T).  K, Vt staged via global_load_lds, XOR-swizzled, dbuf.
__global__ __launch_bounds__(512)
void attn(const unsigned short* __restrict__ Qb,
          const unsigned short* __restrict__ Kb,
          const unsigned short* __restrict__ Vt,
          unsigned short* __restrict__ Ctx) {
  __shared__ char sK[2][8192];   // [64 key][64 d], swizzled
  __shared__ char sV[2][8192];   // [64 d][64 key], swizzled
  const int t = threadIdx.x, wave = t >> 6, lane = t & 63;
  const int l31 = lane & 31, hi = lane >> 5;
  const int bh = blockIdx.x, b = bh >> 4, h = bh & 15;
  const int q0 = blockIdx.y * 256;

  // staging addresses (chunk per wave: rows wave*8 .. wave*8+7)
  const int srow = wave * 8 + (lane >> 3);
  const int sbo = ((lane & 7) * 16) ^ ((srow & 7) << 4);
  const char* gK = (const char*)(Kb + (size_t)b * SEQ * DM + h * 64) + (size_t)srow * (DM * 2) + sbo;
  const char* gV = (const char*)(Vt + ((size_t)bh * 64 + srow) * SEQ) + sbo;

  // Q B-frags: lane holds Q[q = q0+wave*32+l31][d = ks*16 + hi*8 + 0..7]
  bf16x8 qf[4];
  {
    const unsigned short* qp = Qb + ((size_t)b * SEQ + q0 + wave * 32 + l31) * DM + h * 64 + hi * 8;
#pragma unroll
    for (int ks = 0; ks < 4; ++ks) qf[ks] = *(const bf16x8*)(qp + ks * 16);
  }

  f32x16 ot0, ot1;
#pragma unroll
  for (int i = 0; i < 16; ++i) { ot0[i] = 0.f; ot1[i] = 0.f; }
  float m = -1e30f, l = 0.f;

  // prologue stage
  gload16(&sK[0][wave * 1024], gK);
  gload16(&sV[0][wave * 1024], gV);
  __syncthreads();

  for (int kt = 0; kt < SEQ / 64; ++kt) {
    const int pb = kt & 1;
    if (kt + 1 < SEQ / 64) {
      gload16(&sK[pb ^ 1][wave * 1024], gK + (size_t)(kt + 1) * 64 * (DM * 2));
      gload16(&sV[pb ^ 1][wave * 1024], gV + (size_t)(kt + 1) * 128);
    }

    // ---- S^T[key][q] = K . Q  (two 32-key halves)
    f32x16 s0, s1;
#pragma unroll
    for (int i = 0; i < 16; ++i) { s0[i] = 0.f; s1[i] = 0.f; }
    const char* kbase = sK[pb];
#pragma unroll
    for (int ks = 0; ks < 4; ++ks) {
      const int swz = (ks * 32 + hi * 16) ^ ((l31 & 7) << 4);
      bf16x8 kf0 = *(const bf16x8*)(kbase + l31 * 128 + swz);
      s0 = __builtin_amdgcn_mfma_f32_32x32x16_bf16(kf0, qf[ks], s0, 0, 0, 0);
      bf16x8 kf1 = *(const bf16x8*)(kbase + (32 + l31) * 128 + swz);
      s1 = __builtin_amdgcn_mfma_f32_32x32x16_bf16(kf1, qf[ks], s1, 0, 0, 0);
    }

    // ---- online softmax (lane-local q; logits already in log2 domain)
    float pmax = s0[0];
#pragma unroll
    for (int i = 1; i < 16; ++i) pmax = fmaxf(pmax, s0[i]);
#pragma unroll
    for (int i = 0; i < 16; ++i) pmax = fmaxf(pmax, s1[i]);
    pmax = fmaxf(pmax, __shfl_xor(pmax, 32));
    if (__any(pmax > m + 8.f)) {            // defer-max (T13)
      float mn = fmaxf(m, pmax);
      float al = __builtin_amdgcn_exp2f(m - mn);
      m = mn; l *= al;
#pragma unroll
      for (int i = 0; i < 16; ++i) { ot0[i] *= al; ot1[i] *= al; }
    }
    float sum = 0.f;
#pragma unroll
    for (int i = 0; i < 16; ++i) { float p = __builtin_amdgcn_exp2f(s0[i] - m); s0[i] = p; sum += p; }
#pragma unroll
    for (int i = 0; i < 16; ++i) { float p = __builtin_amdgcn_exp2f(s1[i] - m); s1[i] = p; sum += p; }
    sum += __shfl_xor(sum, 32);
    l += sum;

    // ---- O^T += Vt . P^T   (4 key-slices of 16)
    const char* vbase = sV[pb];
#pragma unroll
    for (int sl = 0; sl < 4; ++sl) {
      const f32x16& sp = (sl < 2) ? s0 : s1;
      const int s8 = (sl & 1) * 8;
      uint32_t x0 = cvtpk_bf16(sp[s8 + 0], sp[s8 + 1]);
      uint32_t x1 = cvtpk_bf16(sp[s8 + 2], sp[s8 + 3]);
      uint32_t y0 = cvtpk_bf16(sp[s8 + 4], sp[s8 + 5]);
      uint32_t y1 = cvtpk_bf16(sp[s8 + 6], sp[s8 + 7]);
      uint32_t x0s = (uint32_t)__shfl_xor((int)x0, 32);
      uint32_t x1s = (uint32_t)__shfl_xor((int)x1, 32);
      uint32_t y0s = (uint32_t)__shfl_xor((int)y0, 32);
      uint32_t y1s = (uint32_t)__shfl_xor((int)y1, 32);
      u32x4 wv;
      wv[0] = hi ? y0s : x0;   // keys base+0,1
      wv[1] = hi ? y1s : x1;   // keys base+2,3
      wv[2] = hi ? y0 : x0s;   // keys base+4,5
      wv[3] = hi ? y1 : x1s;   // keys base+6,7
      bf16x8 pf = __builtin_bit_cast(bf16x8, wv);
      {
        const int swz = (sl * 32 + hi * 16) ^ ((l31 & 7) << 4);
        bf16x8 vf0 = *(const bf16x8*)(vbase + l31 * 128 + swz);
        ot0 = __builtin_amdgcn_mfma_f32_32x32x16_bf16(vf0, pf, ot0, 0, 0, 0);
        bf16x8 vf1 = *(const bf16x8*)(vbase + (32 + l31) * 128 + swz);
        ot1 = __builtin_amdgcn_mfma_f32_32x32x16_bf16(vf1, pf, ot1, 0, 0, 0);
      }
    }
    __syncthreads();
  }

  // ---- epilogue: O^T[d][q], lane q = l31, d = dt*32 + rg*8 + hi*4 + i
  float inv = 1.0f / l;
  unsigned short* orow = Ctx + ((size_t)b * SEQ + q0 + wave * 32 + l31) * DM + h * 64;
#pragma unroll
  for (int dt = 0; dt < 2; ++dt) {
    const f32x16& o = dt ? ot1 : ot0;
#pragma unroll
    for (int rg = 0; rg < 4; ++rg) {
      u16x4 pk;
#pragma unroll
      for (int i = 0; i < 4; ++i) pk[i] = f2bf(o[rg * 4 + i] * inv);
      *(u16x4*)(orow + dt * 32 + rg * 8 + hi * 4) = pk;
    }
  }
}

extern "C" void kernel_launch(void* const* d_in, const int* in_sizes, int n_in,
                              void* d_out, int out_size, void* d_ws, size_t ws_size,
                              hipStream_t stream) {
  const float* query = (const float*)d_in[0];
  const float* key   = (const float*)d_in[1];
  const float* value = (const float*)d_in[2];
  const float* Wq = (const float*)d_in[3];
  const float* bq = (const float*)d_in[4];
  const float* Wk = (const float*)d_in[5];
  const float* bk = (const float*)d_in[6];
  const float* Wv = (const float*)d_in[7];
  const float* bv = (const float*)d_in[8];
  const float* Wo = (const float*)d_in[9];
  const float* bo = (const float*)d_in[10];

  char* ws = (char*)d_ws;
  unsigned short* Wt = (unsigned short*)ws;                              // 8 MB
  unsigned short* Qb = (unsigned short*)(ws + 8388608);                  // 16 MB
  unsigned short* Kb = (unsigned short*)(ws + 8388608 + 16777216);       // 16 MB
  unsigned short* Vt = (unsigned short*)(ws + 8388608 + 2 * 16777216);   // 16 MB (transposed V)
  unsigned short* Xc = (unsigned short*)(ws + 8388608 + 3 * 16777216);   // 16 MB (X input / context)

  prep_w<<<dim3(32, 32, 4), 256, 0, stream>>>(Wq, Wk, Wv, Wo, Wt);

  // Q projection (scale 1/8 * log2(e) folded in)
  const float QSCALE = 0.125f * 1.44269504088896340736f;
  cvt_f32_bf16<<<4096, 256, 0, stream>>>(query, Xc, MTOT * DM / 8);
  gemm_bt<0><<<dim3(8, 64), 256, 0, stream>>>(Xc, Wt, bq, Qb, QSCALE);
  cvt_f32_bf16<<<4096, 256, 0, stream>>>(key, Xc, MTOT * DM / 8);
  gemm_bt<0><<<dim3(8, 64), 256, 0, stream>>>(Xc, Wt + (size_t)1048576, bk, Kb, 1.0f);
  cvt_f32_bf16<<<4096, 256, 0, stream>>>(value, Xc, MTOT * DM / 8);
  gemm_bt<2><<<dim3(8, 64), 256, 0, stream>>>(Xc, Wt + (size_t)2 * 1048576, bv, Vt, 1.0f);

  attn<<<dim3(64, 8), 512, 0, stream>>>(Qb, Kb, Vt, Xc);

  gemm_bt<1><<<dim3(8, 64), 256, 0, stream>>>(Xc, Wt + (size_t)3 * 1048576, bo, d_out, 1.0f);
}

// Round 3
// 224.863 us; speedup vs baseline: 1.7375x; 1.0044x over previous
//
#include <hip/hip_runtime.h>
#include <stdint.h>

#define DM 1024
#define SEQ 2048
#define MTOT 8192   // 4*2048

typedef __attribute__((ext_vector_type(8))) short bf16x8;
typedef __attribute__((ext_vector_type(4))) float f32x4;
typedef __attribute__((ext_vector_type(16))) float f32x16;
typedef __attribute__((ext_vector_type(8))) unsigned short u16x8;
typedef __attribute__((ext_vector_type(4))) unsigned short u16x4;
typedef __attribute__((ext_vector_type(4))) uint32_t u32x4;

__device__ __forceinline__ unsigned short f2bf(float x) {
  uint32_t u = __builtin_bit_cast(uint32_t, x);
  u += 0x7fffu + ((u >> 16) & 1u);   // RTNE
  return (unsigned short)(u >> 16);
}

__device__ __forceinline__ uint32_t cvtpk_bf16(float lo, float hi) {
  uint32_t r;
  asm("v_cvt_pk_bf16_f32 %0, %1, %2" : "=v"(r) : "v"(lo), "v"(hi));
  return r;
}

__device__ __forceinline__ void gload16(void* lds, const void* g) {
  __builtin_amdgcn_global_load_lds(
      (const __attribute__((address_space(1))) void*)(uintptr_t)g,
      (__attribute__((address_space(3))) void*)(uintptr_t)lds,
      16, 0, 0);
}

// ---------------- weight transpose + bf16 convert: Wt[n][k] = bf16(W[k][n])
__global__ __launch_bounds__(256)
void prep_w(const float* __restrict__ w0, const float* __restrict__ w1,
            const float* __restrict__ w2, const float* __restrict__ w3,
            unsigned short* __restrict__ Wt) {
  const int z = blockIdx.z;
  const float* W = z == 0 ? w0 : z == 1 ? w1 : z == 2 ? w2 : w3;
  unsigned short* out = Wt + (size_t)z * 1048576;
  __shared__ float tile[32][33];
  const int n0 = blockIdx.x * 32, k0 = blockIdx.y * 32;
  const int tx = threadIdx.x & 31, ty = threadIdx.x >> 5;
#pragma unroll
  for (int j = 0; j < 32; j += 8)
    tile[ty + j][tx] = W[(size_t)(k0 + ty + j) * DM + n0 + tx];
  __syncthreads();
#pragma unroll
  for (int j = 0; j < 32; j += 8)
    out[(size_t)(n0 + ty + j) * DM + k0 + tx] = f2bf(tile[tx][ty + j]);
}

// ---------------- fp32 -> bf16 bulk convert (8 elems/thread)
__global__ __launch_bounds__(256)
void cvt_f32_bf16(const float* __restrict__ in, unsigned short* __restrict__ out, int n8) {
  int i = blockIdx.x * 256 + threadIdx.x;
  if (i < n8) {
    f32x4 a = *(const f32x4*)(in + (size_t)i * 8);
    f32x4 b = *(const f32x4*)(in + (size_t)i * 8 + 4);
    u16x8 o;
#pragma unroll
    for (int j = 0; j < 4; ++j) { o[j] = f2bf(a[j]); o[4 + j] = f2bf(b[j]); }
    *(u16x8*)(out + (size_t)i * 8) = o;
  }
}

// ---------------- bf16 GEMM: C[M][1024] = A[M][1024] @ Wt^T + bias
// Wt is [n][k] row-major bf16. 128x128 tile, BK=64, 4 waves, 16x16x32 MFMA.
// MODE 0: bf16 row-major out (scaled); MODE 1: f32 row-major out;
// MODE 2: bf16 V-transposed out: Vt[(b*16+h)*64+d][s] (d = col%1024 mapping)
template <int MODE>
__global__ __launch_bounds__(256)
void gemm_bt(const unsigned short* __restrict__ A,
             const unsigned short* __restrict__ Wt,
             const float* __restrict__ bias,
             void* __restrict__ C, float oscale) {
  __shared__ char sA[16384];   // [128 rows][64 bf16 = 128B], XOR-swizzled
  __shared__ char sB[16384];
  const int t = threadIdx.x, wave = t >> 6, lane = t & 63;
  const int m0 = blockIdx.y * 128, n0 = blockIdx.x * 128;
  const int wr = (wave >> 1) * 64, wc = (wave & 1) * 64;
  const int lr = lane & 15, kg = lane >> 4;

  f32x4 acc[4][4];
#pragma unroll
  for (int i = 0; i < 4; ++i)
#pragma unroll
    for (int j = 0; j < 4; ++j) acc[i][j] = (f32x4){0.f, 0.f, 0.f, 0.f};

  for (int kt = 0; kt < 16; ++kt) {
    __syncthreads();
#pragma unroll
    for (int i = 0; i < 4; ++i) {
      int c = wave * 4 + i;
      int row = c * 8 + (lane >> 3);
      int bo = ((lane & 7) * 16) ^ ((row & 7) << 4);
      gload16(&sA[c * 1024], (const char*)(A + (size_t)(m0 + row) * DM + kt * 64) + bo);
      gload16(&sB[c * 1024], (const char*)(Wt + (size_t)(n0 + row) * DM + kt * 64) + bo);
    }
    __syncthreads();
#pragma unroll
    for (int ks = 0; ks < 2; ++ks) {
      bf16x8 afr[4], bfr[4];
#pragma unroll
      for (int j = 0; j < 4; ++j) {
        int mr = wr + j * 16 + lr;
        afr[j] = *(const bf16x8*)&sA[mr * 128 + ((ks * 64 + kg * 16) ^ ((mr & 7) << 4))];
        int nr = wc + j * 16 + lr;
        bfr[j] = *(const bf16x8*)&sB[nr * 128 + ((ks * 64 + kg * 16) ^ ((nr & 7) << 4))];
      }
#pragma unroll
      for (int mi = 0; mi < 4; ++mi)
#pragma unroll
        for (int nj = 0; nj < 4; ++nj)
          acc[mi][nj] = __builtin_amdgcn_mfma_f32_16x16x32_bf16(afr[mi], bfr[nj], acc[mi][nj], 0, 0, 0);
    }
  }
  // epilogue: C/D layout col=lane&15, row=(lane>>4)*4+r
#pragma unroll
  for (int nj = 0; nj < 4; ++nj) {
    int col = n0 + wc + nj * 16 + lr;
    float bv = bias[col];
#pragma unroll
    for (int mi = 0; mi < 4; ++mi) {
      int rowseq = m0 + wr + mi * 16 + kg * 4;
      if (MODE == 2) {
        u16x4 pk;
#pragma unroll
        for (int r = 0; r < 4; ++r) pk[r] = f2bf(acc[mi][nj][r] + bv);
        // Vt[(b<<10) + col][s], s = rowseq & 2047, 4 consecutive s
        *(u16x4*)((unsigned short*)C +
                  ((size_t)((rowseq >> 11) << 10) + col) * SEQ + (rowseq & 2047)) = pk;
      } else {
#pragma unroll
        for (int r = 0; r < 4; ++r) {
          float v = (acc[mi][nj][r] + bv) * oscale;
          if (MODE == 1) ((float*)C)[(size_t)(rowseq + r) * DM + col] = v;
          else ((unsigned short*)C)[(size_t)(rowseq + r) * DM + col] = f2bf(v);
        }
      }
    }
  }
}

// ---------------- flash attention, swapped-operand 32x32x16 structure
// Block: 8 waves x 32 q-rows = 256 q for one (b,h). Lane owns q = lane&31.
// S^T = mfma(K, Q); softmax lane-local (exp2 domain, scale folded into Q);
// P^T B-frags built in-register (cvt_pk + cross-half exchange);
// O^T = mfma(Vt, P^T).  K, Vt staged via global_load_lds, XOR-swizzled, dbuf.
__global__ __launch_bounds__(512)
void attn(const unsigned short* __restrict__ Qb,
          const unsigned short* __restrict__ Kb,
          const unsigned short* __restrict__ Vt,
          unsigned short* __restrict__ Ctx) {
  __shared__ char sK[2][8192];   // [64 key][64 d], swizzled
  __shared__ char sV[2][8192];   // [64 d][64 key], swizzled
  const int t = threadIdx.x, wave = t >> 6, lane = t & 63;
  const int l31 = lane & 31, hi = lane >> 5;
  const int bh = blockIdx.x, b = bh >> 4, h = bh & 15;
  const int q0 = blockIdx.y * 256;

  // staging addresses (chunk per wave: rows wave*8 .. wave*8+7)
  const int srow = wave * 8 + (lane >> 3);
  const int sbo = ((lane & 7) * 16) ^ ((srow & 7) << 4);
  const char* gK = (const char*)(Kb + (size_t)b * SEQ * DM + h * 64) + (size_t)srow * (DM * 2) + sbo;
  const char* gV = (const char*)(Vt + ((size_t)bh * 64 + srow) * SEQ) + sbo;

  // Q B-frags: lane holds Q[q = q0+wave*32+l31][d = ks*16 + hi*8 + 0..7]
  bf16x8 qf[4];
  {
    const unsigned short* qp = Qb + ((size_t)b * SEQ + q0 + wave * 32 + l31) * DM + h * 64 + hi * 8;
#pragma unroll
    for (int ks = 0; ks < 4; ++ks) qf[ks] = *(const bf16x8*)(qp + ks * 16);
  }

  f32x16 ot0, ot1;
#pragma unroll
  for (int i = 0; i < 16; ++i) { ot0[i] = 0.f; ot1[i] = 0.f; }
  float m = -1e30f, l = 0.f;

  // prologue stage
  gload16(&sK[0][wave * 1024], gK);
  gload16(&sV[0][wave * 1024], gV);
  __syncthreads();

  for (int kt = 0; kt < SEQ / 64; ++kt) {
    const int pb = kt & 1;
    if (kt + 1 < SEQ / 64) {
      gload16(&sK[pb ^ 1][wave * 1024], gK + (size_t)(kt + 1) * 64 * (DM * 2));
      gload16(&sV[pb ^ 1][wave * 1024], gV + (size_t)(kt + 1) * 128);
    }

    // ---- S^T[key][q] = K . Q  (two 32-key halves)
    f32x16 s0, s1;
#pragma unroll
    for (int i = 0; i < 16; ++i) { s0[i] = 0.f; s1[i] = 0.f; }
    const char* kbase = sK[pb];
#pragma unroll
    for (int ks = 0; ks < 4; ++ks) {
      const int swz = (ks * 32 + hi * 16) ^ ((l31 & 7) << 4);
      bf16x8 kf0 = *(const bf16x8*)(kbase + l31 * 128 + swz);
      s0 = __builtin_amdgcn_mfma_f32_32x32x16_bf16(kf0, qf[ks], s0, 0, 0, 0);
      bf16x8 kf1 = *(const bf16x8*)(kbase + (32 + l31) * 128 + swz);
      s1 = __builtin_amdgcn_mfma_f32_32x32x16_bf16(kf1, qf[ks], s1, 0, 0, 0);
    }

    // ---- online softmax (lane-local q; logits already in log2 domain)
    float pmax = s0[0];
#pragma unroll
    for (int i = 1; i < 16; ++i) pmax = fmaxf(pmax, s0[i]);
#pragma unroll
    for (int i = 0; i < 16; ++i) pmax = fmaxf(pmax, s1[i]);
    pmax = fmaxf(pmax, __shfl_xor(pmax, 32));
    if (__any(pmax > m + 8.f)) {            // defer-max (T13)
      float mn = fmaxf(m, pmax);
      float al = __builtin_amdgcn_exp2f(m - mn);
      m = mn; l *= al;
#pragma unroll
      for (int i = 0; i < 16; ++i) { ot0[i] *= al; ot1[i] *= al; }
    }
    float sum = 0.f;
#pragma unroll
    for (int i = 0; i < 16; ++i) { float p = __builtin_amdgcn_exp2f(s0[i] - m); s0[i] = p; sum += p; }
#pragma unroll
    for (int i = 0; i < 16; ++i) { float p = __builtin_amdgcn_exp2f(s1[i] - m); s1[i] = p; sum += p; }
    sum += __shfl_xor(sum, 32);
    l += sum;

    // ---- O^T += Vt . P^T   (4 key-slices of 16)
    const char* vbase = sV[pb];
#pragma unroll
    for (int sl = 0; sl < 4; ++sl) {
      const f32x16& sp = (sl < 2) ? s0 : s1;
      const int s8 = (sl & 1) * 8;
      uint32_t x0 = cvtpk_bf16(sp[s8 + 0], sp[s8 + 1]);
      uint32_t x1 = cvtpk_bf16(sp[s8 + 2], sp[s8 + 3]);
      uint32_t y0 = cvtpk_bf16(sp[s8 + 4], sp[s8 + 5]);
      uint32_t y1 = cvtpk_bf16(sp[s8 + 6], sp[s8 + 7]);
      uint32_t x0s = (uint32_t)__shfl_xor((int)x0, 32);
      uint32_t x1s = (uint32_t)__shfl_xor((int)x1, 32);
      uint32_t y0s = (uint32_t)__shfl_xor((int)y0, 32);
      uint32_t y1s = (uint32_t)__shfl_xor((int)y1, 32);
      u32x4 wv;
      wv[0] = hi ? y0s : x0;   // keys base+0,1
      wv[1] = hi ? y1s : x1;   // keys base+2,3
      wv[2] = hi ? y0 : x0s;   // keys base+4,5
      wv[3] = hi ? y1 : x1s;   // keys base+6,7
      bf16x8 pf = __builtin_bit_cast(bf16x8, wv);
      {
        const int swz = (sl * 32 + hi * 16) ^ ((l31 & 7) << 4);
        bf16x8 vf0 = *(const bf16x8*)(vbase + l31 * 128 + swz);
        ot0 = __builtin_amdgcn_mfma_f32_32x32x16_bf16(vf0, pf, ot0, 0, 0, 0);
        bf16x8 vf1 = *(const bf16x8*)(vbase + (32 + l31) * 128 + swz);
        ot1 = __builtin_amdgcn_mfma_f32_32x32x16_bf16(vf1, pf, ot1, 0, 0, 0);
      }
    }
    __syncthreads();
  }

  // ---- epilogue: O^T[d][q], lane q = l31, d = dt*32 + rg*8 + hi*4 + i
  float inv = 1.0f / l;
  unsigned short* orow = Ctx + ((size_t)b * SEQ + q0 + wave * 32 + l31) * DM + h * 64;
#pragma unroll
  for (int dt = 0; dt < 2; ++dt) {
    const f32x16& o = dt ? ot1 : ot0;
#pragma unroll
    for (int rg = 0; rg < 4; ++rg) {
      u16x4 pk;
#pragma unroll
      for (int i = 0; i < 4; ++i) pk[i] = f2bf(o[rg * 4 + i] * inv);
      *(u16x4*)(orow + dt * 32 + rg * 8 + hi * 4) = pk;
    }
  }
}

extern "C" void kernel_launch(void* const* d_in, const int* in_sizes, int n_in,
                              void* d_out, int out_size, void* d_ws, size_t ws_size,
                              hipStream_t stream) {
  const float* query = (const float*)d_in[0];
  const float* key   = (const float*)d_in[1];
  const float* value = (const float*)d_in[2];
  const float* Wq = (const float*)d_in[3];
  const float* bq = (const float*)d_in[4];
  const float* Wk = (const float*)d_in[5];
  const float* bk = (const float*)d_in[6];
  const float* Wv = (const float*)d_in[7];
  const float* bv = (const float*)d_in[8];
  const float* Wo = (const float*)d_in[9];
  const float* bo = (const float*)d_in[10];

  char* ws = (char*)d_ws;
  unsigned short* Wt = (unsigned short*)ws;                              // 8 MB
  unsigned short* Qb = (unsigned short*)(ws + 8388608);                  // 16 MB
  unsigned short* Kb = (unsigned short*)(ws + 8388608 + 16777216);       // 16 MB
  unsigned short* Vt = (unsigned short*)(ws + 8388608 + 2 * 16777216);   // 16 MB (transposed V)
  unsigned short* Xc = (unsigned short*)(ws + 8388608 + 3 * 16777216);   // 16 MB (X input / context)

  prep_w<<<dim3(32, 32, 4), 256, 0, stream>>>(Wq, Wk, Wv, Wo, Wt);

  // Q projection (scale 1/8 * log2(e) folded in)
  const float QSCALE = 0.125f * 1.44269504088896340736f;
  cvt_f32_bf16<<<4096, 256, 0, stream>>>(query, Xc, MTOT * DM / 8);
  gemm_bt<0><<<dim3(8, 64), 256, 0, stream>>>(Xc, Wt, bq, Qb, QSCALE);
  cvt_f32_bf16<<<4096, 256, 0, stream>>>(key, Xc, MTOT * DM / 8);
  gemm_bt<0><<<dim3(8, 64), 256, 0, stream>>>(Xc, Wt + (size_t)1048576, bk, Kb, 1.0f);
  cvt_f32_bf16<<<4096, 256, 0, stream>>>(value, Xc, MTOT * DM / 8);
  gemm_bt<2><<<dim3(8, 64), 256, 0, stream>>>(Xc, Wt + (size_t)2 * 1048576, bv, Vt, 1.0f);

  attn<<<dim3(64, 8), 512, 0, stream>>>(Qb, Kb, Vt, Xc);

  gemm_bt<1><<<dim3(8, 64), 256, 0, stream>>>(Xc, Wt + (size_t)3 * 1048576, bo, d_out, 1.0f);
}